// Round 12
// baseline (95.447 us; speedup 1.0000x reference)
//
#include <hip/hip_runtime.h>

#define D 256
#define SCALE 1.69864354f   // sqrt((1/T)*log2e), T=0.5: acc=2.8854*cos -> exp2(acc)=exp(sim/T)
#define EPS 1e-8f

typedef __attribute__((ext_vector_type(8))) __bf16 bf16x8;
typedef __attribute__((ext_vector_type(4))) __bf16 bf16x4;
typedef __attribute__((ext_vector_type(4))) float  f32x4;

// ------ Kernel A: row-normalize [z1;z2] -> bf16 fn (pre-scaled), fused pos --
__global__ __launch_bounds__(256) void normpos_kernel(
    const float* __restrict__ z1, const float* __restrict__ z2,
    __bf16* __restrict__ fn, float* __restrict__ pos, int N) {
  int wid  = threadIdx.x >> 6;
  int lane = threadIdx.x & 63;
  int row  = blockIdx.x * 4 + wid;
  f32x4 a = *(const f32x4*)(z1 + (size_t)row * D + lane * 4);
  f32x4 b = *(const f32x4*)(z2 + (size_t)row * D + lane * 4);
  float s1  = a.x * a.x + a.y * a.y + a.z * a.z + a.w * a.w;
  float s2  = b.x * b.x + b.y * b.y + b.z * b.z + b.w * b.w;
  float dot = a.x * b.x + a.y * b.y + a.z * b.z + a.w * b.w;
  #pragma unroll
  for (int m = 1; m < 64; m <<= 1) {
    s1  += __shfl_xor(s1, m, 64);
    s2  += __shfl_xor(s2, m, 64);
    dot += __shfl_xor(dot, m, 64);
  }
  float inv1 = 1.0f / fmaxf(sqrtf(s1), EPS);
  float inv2 = 1.0f / fmaxf(sqrtf(s2), EPS);
  float q1 = inv1 * SCALE, q2 = inv2 * SCALE;
  bf16x4 o1, o2;
  o1[0] = (__bf16)(a.x * q1); o1[1] = (__bf16)(a.y * q1);
  o1[2] = (__bf16)(a.z * q1); o1[3] = (__bf16)(a.w * q1);
  o2[0] = (__bf16)(b.x * q2); o2[1] = (__bf16)(b.y * q2);
  o2[2] = (__bf16)(b.z * q2); o2[3] = (__bf16)(b.w * q2);
  *(bf16x4*)(fn + (size_t)row * D + lane * 4)       = o1;
  *(bf16x4*)(fn + (size_t)(N + row) * D + lane * 4) = o2;
  if (lane == 0) pos[row] = dot * inv1 * inv2;
}

// -------- Kernel B: denom partials, symmetric upper-triangle MFMA GEMM -----
// R10 structure with LDS packed to EXACTLY 32 KB: epilogue reduce buffers
// alias onto As/Bs (safe after a post-MFMA barrier). 163840/32768 = 5
// blocks/CU (was 4) -> 20 waves/CU for stall hiding. Everything else as R10:
// 128x128 tile, 4 waves, single-buffered, rb<=cb triangle, rowsum ->
// partial[cb][rb-rows], colsum -> partial[rb][cb-rows] (off-diag only).
// Chunk swizzle as inverse-swizzled GLOBAL source + swizzled ds_read.
// mfma_f32_16x16x32_bf16: A/B row/col=lane&15, k=(lane>>4)*8+j;
// C/D col=lane&15, row=(lane>>4)*4+reg  (m89/m91-verified).

__device__ __forceinline__ void stage_tile(const __bf16* __restrict__ row0,
                                           int kk, __bf16* lds, int tid) {
  // 128 rows x 64 k (16 KB) = 1024 chunks of 16B; 4 iters x 256 threads.
  #pragma unroll
  for (int it = 0; it < 4; ++it) {
    int s = it * 256 + tid;        // chunk slot; per-wave base + lane*16B ✓
    int r = s >> 3;                // row in tile
    int p = s & 7;                 // chunk-in-row (LDS position)
    const __bf16* src = row0 + (size_t)r * D + kk * 64 + ((p ^ (r & 7)) << 3);
    __builtin_amdgcn_global_load_lds(
        (const __attribute__((address_space(1))) void*)src,
        (__attribute__((address_space(3))) void*)(lds + s * 8), 16, 0, 0);
  }
}

__global__ __launch_bounds__(256, 5) void denom_kernel(
    const __bf16* __restrict__ fn, float* __restrict__ partial, int twoN) {
  __shared__ __bf16 As[128 * 64];      // 16 KB; total LDS = 32 KB exactly
  __shared__ __bf16 Bs[128 * 64];      // 16 KB

  int tid  = threadIdx.x;
  int wid  = tid >> 6;
  int lane = tid & 63;
  int c = lane & 15;            // frag row/col within 16-tile
  int g = lane >> 4;            // k-group (in) / row-group (out)
  int wr = wid >> 1, wc = wid & 1;

  // decode lower-triangle linear index -> (rb<=cb)
  int bid = blockIdx.x;
  int i = (int)((sqrtf(8.f * (float)bid + 1.f) - 1.f) * 0.5f);
  while ((i + 1) * (i + 2) / 2 <= bid) ++i;
  while (i * (i + 1) / 2 > bid) --i;
  int rb = bid - i * (i + 1) / 2;   // row block  (rb <= cb)
  int cb = i;                       // col block
  const __bf16* Arow0 = fn + (size_t)rb * 128 * D;
  const __bf16* Brow0 = fn + (size_t)cb * 128 * D;

  bool dblk  = (rb == cb);
  bool dwave = dblk && (wr == wc);

  f32x4 acc[4][4] = {};

  stage_tile(Arow0, 0, As, tid);
  stage_tile(Brow0, 0, Bs, tid);

  #pragma unroll
  for (int kk = 0; kk < 4; ++kk) {
    __syncthreads();   // stage complete (vmcnt drained before barrier)
    #pragma unroll
    for (int ks = 0; ks < 2; ++ks) {
      bf16x8 a[4], b[4];
      #pragma unroll
      for (int mi = 0; mi < 4; ++mi) {
        int ar = wr * 64 + mi * 16 + c;
        a[mi] = *(const bf16x8*)((const char*)As + ar * 128 +
                                 ((((ks << 2) + g) ^ (ar & 7)) << 4));
      }
      #pragma unroll
      for (int ni = 0; ni < 4; ++ni) {
        int bc = wc * 64 + ni * 16 + c;
        b[ni] = *(const bf16x8*)((const char*)Bs + bc * 128 +
                                 ((((ks << 2) + g) ^ (bc & 7)) << 4));
      }
      #pragma unroll
      for (int mi = 0; mi < 4; ++mi)
        #pragma unroll
        for (int ni = 0; ni < 4; ++ni)
          acc[mi][ni] = __builtin_amdgcn_mfma_f32_16x16x32_bf16(
              a[mi], b[ni], acc[mi][ni], 0, 0, 0);
    }
    if (kk < 3) {
      __syncthreads();               // protect LDS before restage
      stage_tile(Arow0, kk + 1, As, tid);
      stage_tile(Brow0, kk + 1, Bs, tid);
    }
  }

  // ---- epilogue: e = exp2(acc) (scale pre-folded); 3 wave-uniform paths ----
  float rsum[16];
  float csum[4];
  #pragma unroll
  for (int ii = 0; ii < 16; ++ii) rsum[ii] = 0.f;
  #pragma unroll
  for (int ii = 0; ii < 4; ++ii) csum[ii] = 0.f;

  if (dwave) {
    // diagonal 64x64 sub-tile: rowsum with diag-zero (no colsum needed)
    #pragma unroll
    for (int mi = 0; mi < 4; ++mi)
      #pragma unroll
      for (int ni = 0; ni < 4; ++ni) {
        int colloc = ni * 16 + c;
        #pragma unroll
        for (int r = 0; r < 4; ++r) {
          int rowloc = mi * 16 + g * 4 + r;
          float e = __builtin_amdgcn_exp2f(acc[mi][ni][r]);
          if (rowloc == colloc) e = 0.f;
          rsum[mi * 4 + r] += e;
        }
      }
  } else if (dblk) {
    // off-diag sub-tile of a diagonal block: clean rowsum only
    #pragma unroll
    for (int mi = 0; mi < 4; ++mi)
      #pragma unroll
      for (int ni = 0; ni < 4; ++ni)
        #pragma unroll
        for (int r = 0; r < 4; ++r)
          rsum[mi * 4 + r] += __builtin_amdgcn_exp2f(acc[mi][ni][r]);
  } else {
    // off-diagonal block: rowsum + colsum
    #pragma unroll
    for (int mi = 0; mi < 4; ++mi)
      #pragma unroll
      for (int ni = 0; ni < 4; ++ni)
        #pragma unroll
        for (int r = 0; r < 4; ++r) {
          float e = __builtin_amdgcn_exp2f(acc[mi][ni][r]);
          rsum[mi * 4 + r] += e;
          csum[ni]         += e;
        }
  }

  // row sums: reduce across the 16 column-lanes (lane bits 0-3)
  #pragma unroll
  for (int ii = 0; ii < 16; ++ii) {
    float v = rsum[ii];
    v += __shfl_xor(v, 1, 64);
    v += __shfl_xor(v, 2, 64);
    v += __shfl_xor(v, 4, 64);
    v += __shfl_xor(v, 8, 64);
    rsum[ii] = v;
  }
  if (!dblk) {
    // col sums: reduce across the 4 row-groups g (lane bits 4-5)
    #pragma unroll
    for (int ii = 0; ii < 4; ++ii) {
      float v = csum[ii];
      v += __shfl_xor(v, 16, 64);
      v += __shfl_xor(v, 32, 64);
      csum[ii] = v;
    }
  }

  // ---- alias reduce buffers onto As/Bs (all MFMA reads are done) ----
  __syncthreads();                    // everyone finished reading As/Bs
  float* redR = (float*)As;           // [128][2] row sums, split by wc
  float* redC = (float*)Bs;           // [128][2] col sums, split by wr
  if (c == 0) {
    #pragma unroll
    for (int mi = 0; mi < 4; ++mi)
      #pragma unroll
      for (int r = 0; r < 4; ++r)
        redR[(wr * 64 + mi * 16 + g * 4 + r) * 2 + wc] = rsum[mi * 4 + r];
  }
  if (!dblk && g == 0) {
    #pragma unroll
    for (int ni = 0; ni < 4; ++ni)
      redC[(wc * 64 + ni * 16 + c) * 2 + wr] = csum[ni];
  }
  __syncthreads();
  if (tid < 128) {
    partial[(size_t)cb * twoN + rb * 128 + tid] =
        redR[tid * 2] + redR[tid * 2 + 1];
    if (rb != cb)
      partial[(size_t)rb * twoN + cb * 128 + tid] =
          redC[tid * 2] + redC[tid * 2 + 1];
  }
}

// ---------------- Kernel C1: per-256-row block sums of log(denom), pos -----
__global__ __launch_bounds__(256) void reduce1_kernel(
    const float* __restrict__ partial, const float* __restrict__ pos,
    float* __restrict__ bsum, int twoN, int N, int nsplit) {
  int row = blockIdx.x * 256 + threadIdx.x;
  int wid = threadIdx.x >> 6, lane = threadIdx.x & 63;
  float denom = 0.f;
  for (int s = 0; s < nsplit; ++s) denom += partial[(size_t)s * twoN + row];
  float ld = logf(denom);
  float p  = (row < N) ? pos[row] : 0.f;
  #pragma unroll
  for (int m = 1; m < 64; m <<= 1) {
    ld += __shfl_xor(ld, m, 64);
    p  += __shfl_xor(p, m, 64);
  }
  __shared__ float sld[4], spo[4];
  if (lane == 0) { sld[wid] = ld; spo[wid] = p; }
  __syncthreads();
  if (threadIdx.x == 0) {
    bsum[blockIdx.x]      = sld[0] + sld[1] + sld[2] + sld[3];
    bsum[32 + blockIdx.x] = spo[0] + spo[1] + spo[2] + spo[3];
  }
}

// ---------------- Kernel C2: final scalar loss -----------------------------
__global__ void reduce2_kernel(const float* __restrict__ bsum,
                               float* __restrict__ out, int twoN, int N,
                               int nblk) {
  int t = threadIdx.x;
  float ld = (t < nblk) ? bsum[t] : 0.f;
  float p  = (t < nblk) ? bsum[32 + t] : 0.f;
  #pragma unroll
  for (int m = 1; m < 64; m <<= 1) {
    ld += __shfl_xor(ld, m, 64);
    p  += __shfl_xor(p, m, 64);
  }
  if (t == 0) out[0] = ld / (float)twoN - 2.f * (p / (float)N);
}

extern "C" void kernel_launch(void* const* d_in, const int* in_sizes, int n_in,
                              void* d_out, int out_size, void* d_ws,
                              size_t ws_size, hipStream_t stream) {
  const float* z1 = (const float*)d_in[0];
  const float* z2 = (const float*)d_in[1];
  int N = in_sizes[0] / D;   // 4096
  int twoN = 2 * N;          // 8192
  int nrb = twoN / 128;      // 64 (= nsplit)

  // workspace layout
  __bf16* fn      = (__bf16*)d_ws;                               // 4 MB
  float*  partial = (float*)((char*)d_ws + (size_t)twoN * D * 2);// 2 MB
  float*  pos     = (float*)((char*)partial + (size_t)nrb * twoN * 4);
  float*  bsum    = (float*)((char*)pos + (size_t)N * 4);        // 64 floats

  normpos_kernel<<<N / 4, 256, 0, stream>>>(z1, z2, fn, pos, N);
  int ntri = nrb * (nrb + 1) / 2;  // 2080 upper-triangle blocks
  denom_kernel<<<ntri, 256, 0, stream>>>(fn, partial, twoN);
  int nblk = twoN / 256;  // 32
  reduce1_kernel<<<nblk, 256, 0, stream>>>(partial, pos, bsum, twoN, N, nrb);
  reduce2_kernel<<<1, 64, 0, stream>>>(bsum, (float*)d_out, twoN, N, nblk);
}

// Round 13
// 52.770 us; speedup vs baseline: 1.8087x; 1.8087x over previous
//
#include <hip/hip_runtime.h>
#include <hip/hip_fp8.h>

#define D 256
#define SCALE 1.69864354f   // sqrt((1/T)*log2e), T=0.5: acc=2.8854*cos -> exp2(acc)=exp(sim/T)
#define EPS 1e-8f

typedef __attribute__((ext_vector_type(4))) float f32x4;
typedef long fp8x8;   // 8 packed e4m3 bytes = one MFMA A/B fragment register pair

// ------ Kernel A: row-normalize [z1;z2] -> fp8 fn (pre-scaled), fused pos ---
// Also zeroes the reduce sync counter (runs before reduce1 in stream order).
__global__ __launch_bounds__(256) void normpos_kernel(
    const float* __restrict__ z1, const float* __restrict__ z2,
    unsigned char* __restrict__ fnq, float* __restrict__ pos,
    int* __restrict__ sync, int N) {
  if (blockIdx.x == 0 && threadIdx.x == 0) *sync = 0;
  int wid  = threadIdx.x >> 6;
  int lane = threadIdx.x & 63;
  int row  = blockIdx.x * 4 + wid;
  f32x4 a = *(const f32x4*)(z1 + (size_t)row * D + lane * 4);
  f32x4 b = *(const f32x4*)(z2 + (size_t)row * D + lane * 4);
  float s1  = a.x * a.x + a.y * a.y + a.z * a.z + a.w * a.w;
  float s2  = b.x * b.x + b.y * b.y + b.z * b.z + b.w * b.w;
  float dot = a.x * b.x + a.y * b.y + a.z * b.z + a.w * b.w;
  #pragma unroll
  for (int m = 1; m < 64; m <<= 1) {
    s1  += __shfl_xor(s1, m, 64);
    s2  += __shfl_xor(s2, m, 64);
    dot += __shfl_xor(dot, m, 64);
  }
  float inv1 = 1.0f / fmaxf(sqrtf(s1), EPS);
  float inv2 = 1.0f / fmaxf(sqrtf(s2), EPS);
  float q1 = inv1 * SCALE, q2 = inv2 * SCALE;
  unsigned int w1 = 0, w2 = 0;
  #pragma unroll
  for (int j = 0; j < 4; ++j) {
    w1 |= (unsigned int)__hip_cvt_float_to_fp8(a[j] * q1, __HIP_SATFINITE,
                                               __HIP_E4M3) << (8 * j);
    w2 |= (unsigned int)__hip_cvt_float_to_fp8(b[j] * q2, __HIP_SATFINITE,
                                               __HIP_E4M3) << (8 * j);
  }
  *(unsigned int*)(fnq + (size_t)row * D + lane * 4)       = w1;
  *(unsigned int*)(fnq + (size_t)(N + row) * D + lane * 4) = w2;
  if (lane == 0) pos[row] = dot * inv1 * inv2;
}

// -------- Kernel B: denom partials, fp8 symmetric upper-triangle GEMM ------
// R10 skeleton (128x128 tile, 4 waves, single-buffered, launch_bounds(256,4)
// -- NOT 5, R12 spilled). fp8 halves staged bytes + LDS-read bytes; BK=128
// halves K-steps: 2 kk x 4 ks, 64 MFMA per barrier-pair, 3 barriers total.
// Triangle: rb<=cb; rowsum -> partial[cb][rb-rows], colsum -> partial[rb][
// cb-rows] (off-diag). Reduce buffers alias As/Bs after a post-MFMA barrier.
// Chunk swizzle (16B chunks, 8/row): inverse-swizzled GLOBAL source +
// swizzled ds_read, linear LDS dest (rule #21); residual aliasing 2-way=free.
// mfma_f32_16x16x32_fp8_fp8: A/B row/col=lane&15, k=(lane>>4)*8+j (bytes);
// C/D col=lane&15, row=(lane>>4)*4+reg (dtype-independent, m121-m128).

__device__ __forceinline__ void stage_tile(const unsigned char* __restrict__ row0,
                                           int kk, unsigned char* lds, int tid) {
  // 128 rows x 128 k fp8 (16 KB) = 1024 chunks of 16B; 4 iters x 256 thr.
  #pragma unroll
  for (int it = 0; it < 4; ++it) {
    int s = it * 256 + tid;        // chunk slot; per-wave base + lane*16B ✓
    int r = s >> 3;                // row in tile
    int p = s & 7;                 // chunk-in-row (LDS position)
    const unsigned char* src =
        row0 + (size_t)r * D + kk * 128 + ((p ^ (r & 7)) << 4);
    __builtin_amdgcn_global_load_lds(
        (const __attribute__((address_space(1))) void*)src,
        (__attribute__((address_space(3))) void*)(lds + s * 16), 16, 0, 0);
  }
}

__global__ __launch_bounds__(256, 4) void denom_kernel(
    const unsigned char* __restrict__ fnq, float* __restrict__ partial,
    int twoN) {
  __shared__ unsigned char As[128 * 128];   // 16 KB; total 32 KB
  __shared__ unsigned char Bs[128 * 128];   // 16 KB

  int tid  = threadIdx.x;
  int wid  = tid >> 6;
  int lane = tid & 63;
  int c = lane & 15;            // frag row/col within 16-tile
  int g = lane >> 4;            // k-group (in) / row-group (out)
  int wr = wid >> 1, wc = wid & 1;

  // decode lower-triangle linear index -> (rb<=cb)
  int bid = blockIdx.x;
  int i = (int)((sqrtf(8.f * (float)bid + 1.f) - 1.f) * 0.5f);
  while ((i + 1) * (i + 2) / 2 <= bid) ++i;
  while (i * (i + 1) / 2 > bid) --i;
  int rb = bid - i * (i + 1) / 2;   // row block  (rb <= cb)
  int cb = i;                       // col block
  const unsigned char* Arow0 = fnq + (size_t)rb * 128 * D;
  const unsigned char* Brow0 = fnq + (size_t)cb * 128 * D;

  bool dblk  = (rb == cb);
  bool dwave = dblk && (wr == wc);

  f32x4 acc[4][4] = {};

  stage_tile(Arow0, 0, As, tid);
  stage_tile(Brow0, 0, Bs, tid);

  #pragma unroll
  for (int kk = 0; kk < 2; ++kk) {
    __syncthreads();   // stage complete (vmcnt drained before barrier)
    #pragma unroll
    for (int ks = 0; ks < 4; ++ks) {
      fp8x8 a[4], b[4];
      int q  = (ks << 1) | (g >> 1);   // 16B-chunk index of this k-group
      int h  = (g & 1) << 3;           // 8B half within chunk
      #pragma unroll
      for (int mi = 0; mi < 4; ++mi) {
        int ar = wr * 64 + mi * 16 + c;
        a[mi] = *(const fp8x8*)(As + ar * 128 + ((q ^ (ar & 7)) << 4) + h);
      }
      #pragma unroll
      for (int ni = 0; ni < 4; ++ni) {
        int bc = wc * 64 + ni * 16 + c;
        b[ni] = *(const fp8x8*)(Bs + bc * 128 + ((q ^ (bc & 7)) << 4) + h);
      }
      #pragma unroll
      for (int mi = 0; mi < 4; ++mi)
        #pragma unroll
        for (int ni = 0; ni < 4; ++ni)
          acc[mi][ni] = __builtin_amdgcn_mfma_f32_16x16x32_fp8_fp8(
              a[mi], b[ni], acc[mi][ni], 0, 0, 0);
    }
    if (kk == 0) {
      __syncthreads();               // protect LDS before restage
      stage_tile(Arow0, 1, As, tid);
      stage_tile(Brow0, 1, Bs, tid);
    }
  }

  // ---- epilogue: e = exp2(acc) (scale pre-folded); 3 wave-uniform paths ----
  float rsum[16];
  float csum[4];
  #pragma unroll
  for (int ii = 0; ii < 16; ++ii) rsum[ii] = 0.f;
  #pragma unroll
  for (int ii = 0; ii < 4; ++ii) csum[ii] = 0.f;

  if (dwave) {
    #pragma unroll
    for (int mi = 0; mi < 4; ++mi)
      #pragma unroll
      for (int ni = 0; ni < 4; ++ni) {
        int colloc = ni * 16 + c;
        #pragma unroll
        for (int r = 0; r < 4; ++r) {
          int rowloc = mi * 16 + g * 4 + r;
          float e = __builtin_amdgcn_exp2f(acc[mi][ni][r]);
          if (rowloc == colloc) e = 0.f;
          rsum[mi * 4 + r] += e;
        }
      }
  } else if (dblk) {
    #pragma unroll
    for (int mi = 0; mi < 4; ++mi)
      #pragma unroll
      for (int ni = 0; ni < 4; ++ni)
        #pragma unroll
        for (int r = 0; r < 4; ++r)
          rsum[mi * 4 + r] += __builtin_amdgcn_exp2f(acc[mi][ni][r]);
  } else {
    #pragma unroll
    for (int mi = 0; mi < 4; ++mi)
      #pragma unroll
      for (int ni = 0; ni < 4; ++ni)
        #pragma unroll
        for (int r = 0; r < 4; ++r) {
          float e = __builtin_amdgcn_exp2f(acc[mi][ni][r]);
          rsum[mi * 4 + r] += e;
          csum[ni]         += e;
        }
  }

  // row sums: reduce across the 16 column-lanes (lane bits 0-3)
  #pragma unroll
  for (int ii = 0; ii < 16; ++ii) {
    float v = rsum[ii];
    v += __shfl_xor(v, 1, 64);
    v += __shfl_xor(v, 2, 64);
    v += __shfl_xor(v, 4, 64);
    v += __shfl_xor(v, 8, 64);
    rsum[ii] = v;
  }
  if (!dblk) {
    // col sums: reduce across the 4 row-groups g (lane bits 4-5)
    #pragma unroll
    for (int ii = 0; ii < 4; ++ii) {
      float v = csum[ii];
      v += __shfl_xor(v, 16, 64);
      v += __shfl_xor(v, 32, 64);
      csum[ii] = v;
    }
  }

  // ---- alias reduce buffers onto As/Bs (all MFMA reads are done) ----
  __syncthreads();                    // everyone finished reading As/Bs
  float* redR = (float*)As;           // [128][2] row sums, split by wc
  float* redC = (float*)Bs;           // [128][2] col sums, split by wr
  if (c == 0) {
    #pragma unroll
    for (int mi = 0; mi < 4; ++mi)
      #pragma unroll
      for (int r = 0; r < 4; ++r)
        redR[(wr * 64 + mi * 16 + g * 4 + r) * 2 + wc] = rsum[mi * 4 + r];
  }
  if (!dblk && g == 0) {
    #pragma unroll
    for (int ni = 0; ni < 4; ++ni)
      redC[(wc * 64 + ni * 16 + c) * 2 + wr] = csum[ni];
  }
  __syncthreads();
  if (tid < 128) {
    partial[(size_t)cb * twoN + rb * 128 + tid] =
        redR[tid * 2] + redR[tid * 2 + 1];
    if (rb != cb)
      partial[(size_t)rb * twoN + cb * 128 + tid] =
          redC[tid * 2] + redC[tid * 2 + 1];
  }
}

// ---- Kernel C: per-256-row sums of log(denom), pos; last block finishes ----
__global__ __launch_bounds__(256) void reduce_kernel(
    const float* __restrict__ partial, const float* __restrict__ pos,
    float* __restrict__ bsum, float* __restrict__ out, int* __restrict__ sync,
    int twoN, int N, int nsplit) {
  int row = blockIdx.x * 256 + threadIdx.x;
  int wid = threadIdx.x >> 6, lane = threadIdx.x & 63;
  float denom = 0.f;
  for (int s = 0; s < nsplit; ++s) denom += partial[(size_t)s * twoN + row];
  float ld = logf(denom);
  float p  = (row < N) ? pos[row] : 0.f;
  #pragma unroll
  for (int m = 1; m < 64; m <<= 1) {
    ld += __shfl_xor(ld, m, 64);
    p  += __shfl_xor(p, m, 64);
  }
  __shared__ float sld[4], spo[4];
  __shared__ int lastf;
  if (lane == 0) { sld[wid] = ld; spo[wid] = p; }
  __syncthreads();
  if (threadIdx.x == 0) {
    bsum[blockIdx.x]                = sld[0] + sld[1] + sld[2] + sld[3];
    bsum[gridDim.x + blockIdx.x]    = spo[0] + spo[1] + spo[2] + spo[3];
    __threadfence();
    lastf = (atomicAdd(sync, 1) == (int)gridDim.x - 1);
  }
  __syncthreads();
  if (lastf && threadIdx.x < 64) {
    __threadfence();   // acquire other blocks' bsum
    int t = threadIdx.x;
    int nb = gridDim.x;
    float l2 = (t < nb) ? bsum[t] : 0.f;
    float p2 = (t < nb) ? bsum[nb + t] : 0.f;
    #pragma unroll
    for (int m = 1; m < 64; m <<= 1) {
      l2 += __shfl_xor(l2, m, 64);
      p2 += __shfl_xor(p2, m, 64);
    }
    if (t == 0) out[0] = l2 / (float)twoN - 2.f * (p2 / (float)N);
  }
}

extern "C" void kernel_launch(void* const* d_in, const int* in_sizes, int n_in,
                              void* d_out, int out_size, void* d_ws,
                              size_t ws_size, hipStream_t stream) {
  const float* z1 = (const float*)d_in[0];
  const float* z2 = (const float*)d_in[1];
  int N = in_sizes[0] / D;   // 4096
  int twoN = 2 * N;          // 8192
  int nrb = twoN / 128;      // 64 (= nsplit)

  // workspace layout
  unsigned char* fnq = (unsigned char*)d_ws;                     // 2 MB fp8
  float* partial = (float*)((char*)d_ws + (size_t)twoN * D);     // 2 MB
  float* pos     = (float*)((char*)partial + (size_t)nrb * twoN * 4);
  float* bsum    = (float*)((char*)pos + (size_t)N * 4);         // 64 floats
  int*   sync    = (int*)((char*)bsum + 256 * 4);

  normpos_kernel<<<N / 4, 256, 0, stream>>>(z1, z2, fnq, pos, sync, N);
  int ntri = nrb * (nrb + 1) / 2;  // 2080 upper-triangle blocks
  denom_kernel<<<ntri, 256, 0, stream>>>(fnq, partial, twoN);
  int nblk = twoN / 256;  // 32
  reduce_kernel<<<nblk, 256, 0, stream>>>(partial, pos, bsum, (float*)d_out,
                                          sync, twoN, N, nrb);
}